// Round 7
// baseline (1020.231 us; speedup 1.0000x reference)
//
#include <hip/hip_runtime.h>
#include <math.h>

#define Bsz  4
#define Tlen 2048
#define Dm   1024
#define Hh   8
#define dh   128
#define Mrows (Bsz * Tlen)   // 8192
#define CH   128             // chunk length for pass 2
#define NCH  (Tlen / CH)     // 16 chunks

typedef __attribute__((ext_vector_type(8))) short  s16x8;
typedef __attribute__((ext_vector_type(4))) float  f32x4;

// DPP cross-lane add at VALU latency.
#define DPP_ADD(x, ctrl) \
    ((x) + __int_as_float(__builtin_amdgcn_update_dpp( \
        0, __float_as_int(x), (ctrl), 0xf, 0xf, true)))
// ds_swizzle xor16 (BitMode: xor_mask=16, and_mask=0x1F)
#define SWZ_ADD16(x) \
    ((x) + __int_as_float(__builtin_amdgcn_ds_swizzle(__float_as_int(x), 0x401F)))

__device__ inline unsigned short f2b_rne(float f) {
    unsigned int u = __float_as_uint(f);
    u += 0x7FFFu + ((u >> 16) & 1u);
    return (unsigned short)(u >> 16);
}
// bf16 (low 16 bits) -> fp32
__device__ inline float blo(unsigned int u) { return __uint_as_float(u << 16); }
// bf16 (high 16 bits) -> fp32
__device__ inline float bhi(unsigned int u) { return __uint_as_float(u & 0xFFFF0000u); }

__global__ __launch_bounds__(256) void cvt_f32_bf16(const float* __restrict__ in,
                                                    unsigned short* __restrict__ out)
{
    const size_t i = ((size_t)blockIdx.x * 256 + threadIdx.x) * 4;
    float4 v = *(const float4*)&in[i];
    ushort4 o;
    o.x = f2b_rne(v.x); o.y = f2b_rne(v.y);
    o.z = f2b_rne(v.z); o.w = f2b_rne(v.w);
    *(ushort4*)&out[i] = o;
}

// ---------------------------------------------------------------------------
// bf16 MFMA GEMM: val = sum_k A[m][k]*W[n][k] (+bias)
// mode 0: Yf = val;  mode 1: Yf = sigmoid(val);  mode 2: Y16 = bf16(val)
// ---------------------------------------------------------------------------
__global__ __launch_bounds__(256) void gemm_bf16(const unsigned short* __restrict__ A,
                                                 const unsigned short* __restrict__ Wt,
                                                 const float* __restrict__ bias,
                                                 float* __restrict__ Yf,
                                                 unsigned short* __restrict__ Y16,
                                                 int mode)
{
    __shared__ __align__(16) unsigned short As[128 * 32];
    __shared__ __align__(16) unsigned short Bs[128 * 32];

    const int tid   = threadIdx.x;
    const int w     = tid >> 6;
    const int lane  = tid & 63;
    const int r4    = lane >> 2;
    const int p4    = lane & 3;
    const int row16 = lane & 15;
    const int quad  = lane >> 4;

    const int m0 = blockIdx.y * 128;
    const int n0 = blockIdx.x * 128;
    const int wm = (w >> 1) * 64;
    const int wn = (w & 1) * 64;

    f32x4 acc[4][4];
#pragma unroll
    for (int i = 0; i < 4; ++i)
#pragma unroll
        for (int j = 0; j < 4; ++j)
            acc[i][j] = (f32x4){0.f, 0.f, 0.f, 0.f};

    for (int k0 = 0; k0 < 1024; k0 += 32) {
        __syncthreads();
#pragma unroll
        for (int c = 0; c < 2; ++c) {
            const int ml  = w * 32 + c * 16 + r4;
            const int swz = (ml >> 1) & 3;
            const unsigned short* ga = A  + (size_t)(m0 + ml) * 1024 + k0 + ((p4 ^ swz) << 3);
            const unsigned short* gb = Wt + (size_t)(n0 + ml) * 1024 + k0 + ((p4 ^ swz) << 3);
            __builtin_amdgcn_global_load_lds(
                (const __attribute__((address_space(1))) void*)ga,
                (__attribute__((address_space(3))) void*)&As[(w * 32 + c * 16) * 32], 16, 0, 0);
            __builtin_amdgcn_global_load_lds(
                (const __attribute__((address_space(1))) void*)gb,
                (__attribute__((address_space(3))) void*)&Bs[(w * 32 + c * 16) * 32], 16, 0, 0);
        }
        __syncthreads();

        s16x8 af[4], bf[4];
#pragma unroll
        for (int bm = 0; bm < 4; ++bm) {
            const int ml  = wm + bm * 16 + row16;
            const int pos = quad ^ ((ml >> 1) & 3);
            af[bm] = *(const s16x8*)&As[ml * 32 + pos * 8];
        }
#pragma unroll
        for (int bn = 0; bn < 4; ++bn) {
            const int nl  = wn + bn * 16 + row16;
            const int pos = quad ^ ((nl >> 1) & 3);
            bf[bn] = *(const s16x8*)&Bs[nl * 32 + pos * 8];
        }
#pragma unroll
        for (int bm = 0; bm < 4; ++bm)
#pragma unroll
            for (int bn = 0; bn < 4; ++bn)
                acc[bm][bn] = __builtin_amdgcn_mfma_f32_16x16x32_bf16(af[bm], bf[bn], acc[bm][bn], 0, 0, 0);
    }

#pragma unroll
    for (int bm = 0; bm < 4; ++bm) {
        const int row = m0 + wm + bm * 16 + quad * 4;
#pragma unroll
        for (int bn = 0; bn < 4; ++bn) {
            const int col = n0 + wn + bn * 16 + row16;
            const float bb = bias ? bias[col] : 0.f;
#pragma unroll
            for (int r = 0; r < 4; ++r) {
                float val = acc[bm][bn][r] + bb;
                if (mode == 1) val = 1.f / (1.f + __expf(-val));
                if (mode == 2) Y16[(size_t)(row + r) * 1024 + col] = f2b_rne(val);
                else           Yf [(size_t)(row + r) * 1024 + col] = val;
            }
        }
    }
}

// ---------------------------------------------------------------------------
// Prep: L2-normalize K,V rows; emit K16 (bf16 normalized K) and P16 packed
// (lr, lr*v_norm) bf16 pairs (one uint per element).  No fp32 writebacks.
// ---------------------------------------------------------------------------
__global__ __launch_bounds__(256) void l2norm_prep(const float* __restrict__ Kb,
                                                   const float* __restrict__ Vb,
                                                   const float* __restrict__ LRb,
                                                   unsigned short* __restrict__ K16,
                                                   unsigned int* __restrict__ P16)
{
    const int gtid = blockIdx.x * 256 + threadIdx.x;
    const int row  = gtid >> 6;
    const int lane = threadIdx.x & 63;
    const size_t base = (size_t)row * dh + lane * 2;

    float2 k2 = *(const float2*)&Kb[base];
    float2 v2 = *(const float2*)&Vb[base];
    float2 l2 = *(const float2*)&LRb[base];
    float sk = k2.x * k2.x + k2.y * k2.y;
    float sv = v2.x * v2.x + v2.y * v2.y;
#pragma unroll
    for (int off = 1; off < 64; off <<= 1) {
        sk += __shfl_xor(sk, off);
        sv += __shfl_xor(sv, off);
    }
    const float rk = 1.f / fmaxf(sqrtf(sk), 1e-12f);
    const float rv = 1.f / fmaxf(sqrtf(sv), 1e-12f);
    k2.x *= rk; k2.y *= rk;
    v2.x *= rv; v2.y *= rv;

    const unsigned int pk = (unsigned int)f2b_rne(k2.x) |
                            ((unsigned int)f2b_rne(k2.y) << 16);
    ((unsigned int*)K16)[base >> 1] = pk;

    uint2 pp;
    pp.x = (unsigned int)f2b_rne(l2.x) | ((unsigned int)f2b_rne(l2.x * v2.x) << 16);
    pp.y = (unsigned int)f2b_rne(l2.y) | ((unsigned int)f2b_rne(l2.y * v2.y) << 16);
    *(uint2*)&P16[base] = pp;
}

// ---------------------------------------------------------------------------
// Pass 1: serial coef-only scan (bf16 inputs, ring-16 prefetch).
// Wave = 2 rows x 32 lanes, 4 state cols/lane.  2048 waves (2/SIMD).
// Per step: 2 loads (k bf16x4 = 8B, (lr,lrv) pair = 4B), d1 = w.k,
// butterfly (4 DPP + 1 swizzle), coef = lrv - lr*d1, w += coef*k.
// U stored transposed [bh, i, t] bf16 (16B store per row per 8 steps).
// W checkpointed bf16 at every chunk start.
// ---------------------------------------------------------------------------
__global__ __launch_bounds__(64) void scan_coef(const unsigned short* __restrict__ K16,
                                                const unsigned int* __restrict__ P16,
                                                unsigned short* __restrict__ Ut,
                                                unsigned short* __restrict__ Wcp)
{
    const int bid = blockIdx.x;            // 0..2047
    const int bh  = bid & 31;              // all 64 blocks of a bh on one XCD
    const int rg  = bid >> 5;              // 0..63
    const int lane = threadIdx.x;
    const int rl   = lane >> 5;            // 0..1 (row within wave)
    const int c32  = lane & 31;            // col chunk (4 cols)
    const int row  = rg * 2 + rl;          // 0..127

    const int b = bh >> 3, h = bh & 7;
    const size_t ebase = (size_t)b * Tlen * Dm + (size_t)h * dh;  // element offset
    const unsigned short* kp = K16 + ebase + c32 * 4;
    const unsigned int*   pp = P16 + ebase + row;
    unsigned short* up = Ut + ((size_t)bh * dh + row) * Tlen;

    float w0 = 0.f, w1 = 0.f, w2 = 0.f, w3 = 0.f;

    // ring-16 prefetch
    uint2         krr[16];
    unsigned int  pv[16];
#pragma unroll
    for (int u = 0; u < 16; ++u) {
        const size_t off = (size_t)u * Dm;
        krr[u] = *(const uint2*)(kp + off);
        pv[u]  = pp[off];
    }

    float o8[8];

    for (int t = 0; t < Tlen; t += 8) {
        if ((t & (CH - 1)) == 0) {
            const int c = t >> 7;
            uint2 wc;
            wc.x = (unsigned int)f2b_rne(w0) | ((unsigned int)f2b_rne(w1) << 16);
            wc.y = (unsigned int)f2b_rne(w2) | ((unsigned int)f2b_rne(w3) << 16);
            *(uint2*)&Wcp[(((size_t)bh * NCH + c) * dh + row) * dh + c32 * 4] = wc;
        }
#pragma unroll
        for (int u = 0; u < 8; ++u) {
            const int slot = (t + u) & 15;
            const uint2 kk = krr[slot];
            const unsigned int pvv = pv[slot];

            // prefetch distance 16 (tn uniform -> sALU addr, saddr loads)
            int tn = t + u + 16; if (tn > Tlen - 1) tn = Tlen - 1;
            const size_t offn = (size_t)tn * Dm;
            krr[slot] = *(const uint2*)(kp + offn);
            pv[slot]  = pp[offn];

            const float k0 = blo(kk.x), k1 = bhi(kk.x);
            const float k2 = blo(kk.y), k3 = bhi(kk.y);
            const float lr  = blo(pvv);
            const float lrv = bhi(pvv);

            float d1 = fmaf(w1, k1, w0 * k0) + fmaf(w3, k3, w2 * k2);
            d1 = DPP_ADD(d1, 0xB1);    // xor1
            d1 = DPP_ADD(d1, 0x4E);    // xor2
            d1 = DPP_ADD(d1, 0x141);   // xor4 (half-mirror)
            d1 = DPP_ADD(d1, 0x140);   // xor8 (row-mirror)
            d1 = SWZ_ADD16(d1);        // xor16 -> all 32 lanes of the row

            const float coef = fmaf(-lr, d1, lrv);
            w0 = fmaf(coef, k0, w0); w1 = fmaf(coef, k1, w1);
            w2 = fmaf(coef, k2, w2); w3 = fmaf(coef, k3, w3);
            o8[u] = coef;
        }
        // coef is row-uniform: lane 0 of each row packs 8 bf16 -> one 16B store
        uint4 pk;
        pk.x = (unsigned int)f2b_rne(o8[0]) | ((unsigned int)f2b_rne(o8[1]) << 16);
        pk.y = (unsigned int)f2b_rne(o8[2]) | ((unsigned int)f2b_rne(o8[3]) << 16);
        pk.z = (unsigned int)f2b_rne(o8[4]) | ((unsigned int)f2b_rne(o8[5]) << 16);
        pk.w = (unsigned int)f2b_rne(o8[6]) | ((unsigned int)f2b_rne(o8[7]) << 16);
        if (c32 == 0)
            *(uint4*)&up[t] = pk;
    }
}

// ---------------------------------------------------------------------------
// Pass 2: per 128-chunk output via MFMA.
//   S = mask_{s<=t}(Q_c K_c^T)  (bf16 in LDS, +8 pad)
//   O = S @ U_c + Q_c @ Wcp^T   -> Obb (bf16, [b,t,h,i])
// Grid: B*H*NCH = 512 blocks, 256 threads.
// ---------------------------------------------------------------------------
__global__ __launch_bounds__(256) void chunk_o(const unsigned short* __restrict__ Q16,
                                               const unsigned short* __restrict__ K16,
                                               const unsigned short* __restrict__ Ut,
                                               const unsigned short* __restrict__ Wcp,
                                               unsigned short* __restrict__ Obb)
{
    __shared__ __align__(16) unsigned short As[128 * 32];
    __shared__ __align__(16) unsigned short Bs[128 * 32];
    __shared__ __align__(16) unsigned short Sb[128 * 136];   // +8 pad

    const int blk = blockIdx.x;
    const int c   = blk & (NCH - 1);
    const int bh  = blk >> 4;
    const int b   = bh >> 3, h = bh & 7;

    const int tid   = threadIdx.x;
    const int w     = tid >> 6;
    const int lane  = tid & 63;
    const int r4    = lane >> 2;
    const int p4    = lane & 3;
    const int row16 = lane & 15;
    const int quad  = lane >> 4;
    const int wm = (w >> 1) * 64;
    const int wn = (w & 1) * 64;

    const size_t qkbase = (size_t)b * Tlen * Dm + (size_t)(c * CH) * Dm + (size_t)h * dh;
    const size_t ubase  = (size_t)bh * dh * Tlen + (size_t)c * CH;       // + i*Tlen + s
    const size_t wbase  = ((size_t)bh * NCH + c) * dh * dh;              // + i*dh + j

    f32x4 acc[4][4];
#pragma unroll
    for (int i = 0; i < 4; ++i)
#pragma unroll
        for (int j = 0; j < 4; ++j)
            acc[i][j] = (f32x4){0.f, 0.f, 0.f, 0.f};

    // ---- Stage 1: S = Q K^T  (inner j = 0..127)
    for (int k0 = 0; k0 < 128; k0 += 32) {
        __syncthreads();
#pragma unroll
        for (int cc = 0; cc < 2; ++cc) {
            const int ml  = w * 32 + cc * 16 + r4;
            const int swz = (ml >> 1) & 3;
            const unsigned short* ga = Q16 + qkbase + (size_t)ml * Dm + k0 + ((p4 ^ swz) << 3);
            const unsigned short* gb = K16 + qkbase + (size_t)ml * Dm + k0 + ((p4 ^ swz) << 3);
            __builtin_amdgcn_global_load_lds(
                (const __attribute__((address_space(1))) void*)ga,
                (__attribute__((address_space(3))) void*)&As[(w * 32 + cc * 16) * 32], 16, 0, 0);
            __builtin_amdgcn_global_load_lds(
                (const __attribute__((address_space(1))) void*)gb,
                (__attribute__((address_space(3))) void*)&Bs[(w * 32 + cc * 16) * 32], 16, 0, 0);
        }
        __syncthreads();

        s16x8 af[4], bf[4];
#pragma unroll
        for (int bm = 0; bm < 4; ++bm) {
            const int ml  = wm + bm * 16 + row16;
            const int pos = quad ^ ((ml >> 1) & 3);
            af[bm] = *(const s16x8*)&As[ml * 32 + pos * 8];
        }
#pragma unroll
        for (int bn = 0; bn < 4; ++bn) {
            const int nl  = wn + bn * 16 + row16;
            const int pos = quad ^ ((nl >> 1) & 3);
            bf[bn] = *(const s16x8*)&Bs[nl * 32 + pos * 8];
        }
#pragma unroll
        for (int bm = 0; bm < 4; ++bm)
#pragma unroll
            for (int bn = 0; bn < 4; ++bn)
                acc[bm][bn] = __builtin_amdgcn_mfma_f32_16x16x32_bf16(af[bm], bf[bn], acc[bm][bn], 0, 0, 0);
    }

    // mask (s <= t), convert, write to Sb; reset acc
#pragma unroll
    for (int bm = 0; bm < 4; ++bm) {
#pragma unroll
        for (int bn = 0; bn < 4; ++bn) {
            const int s_loc = wn + bn * 16 + row16;
#pragma unroll
            for (int r = 0; r < 4; ++r) {
                const int t_loc = wm + bm * 16 + quad * 4 + r;
                const float val = (s_loc <= t_loc) ? acc[bm][bn][r] : 0.f;
                Sb[t_loc * 136 + s_loc] = f2b_rne(val);
            }
            acc[bm][bn] = (f32x4){0.f, 0.f, 0.f, 0.f};
        }
    }

    // ---- Stage 2a: O += S @ U  (inner s = 0..127)
    for (int k0 = 0; k0 < 128; k0 += 32) {
        __syncthreads();
#pragma unroll
        for (int cc = 0; cc < 2; ++cc) {
            const int nl  = w * 32 + cc * 16 + r4;
            const int swz = (nl >> 1) & 3;
            const unsigned short* gb = Ut + ubase + (size_t)nl * Tlen + k0 + ((p4 ^ swz) << 3);
            __builtin_amdgcn_global_load_lds(
                (const __attribute__((address_space(1))) void*)gb,
                (__attribute__((address_space(3))) void*)&Bs[(w * 32 + cc * 16) * 32], 16, 0, 0);
        }
        __syncthreads();

        s16x8 af[4], bf[4];
#pragma unroll
        for (int bm = 0; bm < 4; ++bm) {
            const int ml = wm + bm * 16 + row16;
            af[bm] = *(const s16x8*)&Sb[ml * 136 + k0 + quad * 8];
        }
#pragma unroll
        for (int bn = 0; bn < 4; ++bn) {
            const int nl  = wn + bn * 16 + row16;
            const int pos = quad ^ ((nl >> 1) & 3);
            bf[bn] = *(const s16x8*)&Bs[nl * 32 + pos * 8];
        }
#pragma unroll
        for (int bm = 0; bm < 4; ++bm)
#pragma unroll
            for (int bn = 0; bn < 4; ++bn)
                acc[bm][bn] = __builtin_amdgcn_mfma_f32_16x16x32_bf16(af[bm], bf[bn], acc[bm][bn], 0, 0, 0);
    }

    // ---- Stage 2b: O += Q @ Wcp^T  (inner j = 0..127)
    for (int k0 = 0; k0 < 128; k0 += 32) {
        __syncthreads();
#pragma unroll
        for (int cc = 0; cc < 2; ++cc) {
            const int ml  = w * 32 + cc * 16 + r4;
            const int swz = (ml >> 1) & 3;
            const unsigned short* ga = Q16 + qkbase + (size_t)ml * Dm + k0 + ((p4 ^ swz) << 3);
            const unsigned short* gb = Wcp + wbase + (size_t)ml * dh + k0 + ((p4 ^ swz) << 3);
            __builtin_amdgcn_global_load_lds(
                (const __attribute__((address_space(1))) void*)ga,
                (__attribute__((address_space(3))) void*)&As[(w * 32 + cc * 16) * 32], 16, 0, 0);
            __builtin_amdgcn_global_load_lds(
                (const __attribute__((address_space(1))) void*)gb,
                (__attribute__((address_space(3))) void*)&Bs[(w * 32 + cc * 16) * 32], 16, 0, 0);
        }
        __syncthreads();

        s16x8 af[4], bf[4];
#pragma unroll
        for (int bm = 0; bm < 4; ++bm) {
            const int ml  = wm + bm * 16 + row16;
            const int pos = quad ^ ((ml >> 1) & 3);
            af[bm] = *(const s16x8*)&As[ml * 32 + pos * 8];
        }
#pragma unroll
        for (int bn = 0; bn < 4; ++bn) {
            const int nl  = wn + bn * 16 + row16;
            const int pos = quad ^ ((nl >> 1) & 3);
            bf[bn] = *(const s16x8*)&Bs[nl * 32 + pos * 8];
        }
#pragma unroll
        for (int bm = 0; bm < 4; ++bm)
#pragma unroll
            for (int bn = 0; bn < 4; ++bn)
                acc[bm][bn] = __builtin_amdgcn_mfma_f32_16x16x32_bf16(af[bm], bf[bn], acc[bm][bn], 0, 0, 0);
    }

    // epilogue: Obb[b, c*128 + t_loc, h, i_loc] bf16
#pragma unroll
    for (int bm = 0; bm < 4; ++bm) {
#pragma unroll
        for (int bn = 0; bn < 4; ++bn) {
            const int i_loc = wn + bn * 16 + row16;
#pragma unroll
            for (int r = 0; r < 4; ++r) {
                const int t_loc = wm + bm * 16 + quad * 4 + r;
                Obb[qkbase + (size_t)t_loc * Dm + i_loc] = f2b_rne(acc[bm][bn][r]);
            }
        }
    }
}

// ---------------------------------------------------------------------------
extern "C" void kernel_launch(void* const* d_in, const int* in_sizes, int n_in,
                              void* d_out, int out_size, void* d_ws, size_t ws_size,
                              hipStream_t stream)
{
    const float* x    = (const float*)d_in[0];
    const float* Wq   = (const float*)d_in[1];
    const float* Wk   = (const float*)d_in[2];
    const float* Wv   = (const float*)d_in[3];
    const float* Wo   = (const float*)d_in[4];
    const float* Wlr  = (const float*)d_in[5];
    const float* b_lr = (const float*)d_in[6];

    float* ws = (float*)d_ws;
    const size_t S  = (size_t)Mrows * Dm;    // 8388608
    const size_t SW = (size_t)Dm * Dm;       // 1048576
    float* Kb  = ws;
    float* Vb  = ws + S;
    float* LRb = ws + 2 * S;
    unsigned short* xb   = (unsigned short*)(ws + 3 * S);  // S bf16
    unsigned short* Wcp  = xb;                             // alias: xb dead before pass 1
    unsigned short* Q16  = xb + S;
    unsigned short* K16  = Q16 + S;
    unsigned short* Ut   = K16 + S;                        // S bf16 (= B*H*dh*T)
    unsigned short* Obb  = Ut + S;
    unsigned short* Wqb  = Obb + S;
    unsigned short* Wkb  = Wqb + SW;
    unsigned short* Wvb  = Wkb + SW;
    unsigned short* Wlrb = Wvb + SW;
    unsigned short* Wob  = Wlrb + SW;
    unsigned int*   P16  = (unsigned int*)(Wob + SW);      // S uints

    cvt_f32_bf16<<<S / 1024, 256, 0, stream>>>(x, xb);
    cvt_f32_bf16<<<SW / 1024, 256, 0, stream>>>(Wq, Wqb);
    cvt_f32_bf16<<<SW / 1024, 256, 0, stream>>>(Wk, Wkb);
    cvt_f32_bf16<<<SW / 1024, 256, 0, stream>>>(Wv, Wvb);
    cvt_f32_bf16<<<SW / 1024, 256, 0, stream>>>(Wlr, Wlrb);
    cvt_f32_bf16<<<SW / 1024, 256, 0, stream>>>(Wo, Wob);

    dim3 gg(Dm / 128, Mrows / 128);   // (8, 64)
    gemm_bf16<<<gg, 256, 0, stream>>>(xb, Wqb, nullptr, nullptr, Q16, 2);  // Q -> bf16 only
    gemm_bf16<<<gg, 256, 0, stream>>>(xb, Wkb, nullptr, Kb, nullptr, 0);
    gemm_bf16<<<gg, 256, 0, stream>>>(xb, Wvb, nullptr, Vb, nullptr, 0);
    gemm_bf16<<<gg, 256, 0, stream>>>(xb, Wlrb, b_lr, LRb, nullptr, 1);    // fused sigmoid

    l2norm_prep<<<(Bsz * Tlen * Hh) / 4, 256, 0, stream>>>(Kb, Vb, LRb, K16, P16);

    scan_coef<<<Bsz * Hh * 64, 64, 0, stream>>>(K16, P16, Ut, Wcp);

    chunk_o<<<Bsz * Hh * NCH, 256, 0, stream>>>(Q16, K16, Ut, Wcp, Obb);

    gemm_bf16<<<gg, 256, 0, stream>>>(Obb, Wob, nullptr, (float*)d_out, nullptr, 0);
}

// Round 8
// 645.052 us; speedup vs baseline: 1.5816x; 1.5816x over previous
//
#include <hip/hip_runtime.h>
#include <math.h>

#define Bsz  4
#define Tlen 2048
#define Dm   1024
#define Hh   8
#define dh   128
#define Mrows (Bsz * Tlen)   // 8192
#define CH   128             // chunk length for pass 2
#define NCH  (Tlen / CH)     // 16 chunks

typedef __attribute__((ext_vector_type(8))) short  s16x8;
typedef __attribute__((ext_vector_type(4))) float  f32x4;

// DPP cross-lane add at VALU latency.
#define DPP_ADD(x, ctrl) \
    ((x) + __int_as_float(__builtin_amdgcn_update_dpp( \
        0, __float_as_int(x), (ctrl), 0xf, 0xf, true)))
// ds_swizzle xor16 (BitMode: xor_mask=16, and_mask=0x1F)
#define SWZ_ADD16(x) \
    ((x) + __int_as_float(__builtin_amdgcn_ds_swizzle(__float_as_int(x), 0x401F)))

__device__ inline unsigned short f2b_rne(float f) {
    unsigned int u = __float_as_uint(f);
    u += 0x7FFFu + ((u >> 16) & 1u);
    return (unsigned short)(u >> 16);
}
// bf16 (low 16 bits) -> fp32
__device__ inline float blo(unsigned int u) { return __uint_as_float(u << 16); }
// bf16 (high 16 bits) -> fp32
__device__ inline float bhi(unsigned int u) { return __uint_as_float(u & 0xFFFF0000u); }

__global__ __launch_bounds__(256) void cvt_f32_bf16(const float* __restrict__ in,
                                                    unsigned short* __restrict__ out)
{
    const size_t i = ((size_t)blockIdx.x * 256 + threadIdx.x) * 4;
    float4 v = *(const float4*)&in[i];
    ushort4 o;
    o.x = f2b_rne(v.x); o.y = f2b_rne(v.y);
    o.z = f2b_rne(v.z); o.w = f2b_rne(v.w);
    *(ushort4*)&out[i] = o;
}

// ---------------------------------------------------------------------------
// bf16 MFMA GEMM: val = sum_k A[m][k]*W[n][k] (+bias)
// mode 0: Yf = val;  mode 1: Yf = sigmoid(val);  mode 2: Y16 = bf16(val)
// ---------------------------------------------------------------------------
__global__ __launch_bounds__(256) void gemm_bf16(const unsigned short* __restrict__ A,
                                                 const unsigned short* __restrict__ Wt,
                                                 const float* __restrict__ bias,
                                                 float* __restrict__ Yf,
                                                 unsigned short* __restrict__ Y16,
                                                 int mode)
{
    __shared__ __align__(16) unsigned short As[128 * 32];
    __shared__ __align__(16) unsigned short Bs[128 * 32];

    const int tid   = threadIdx.x;
    const int w     = tid >> 6;
    const int lane  = tid & 63;
    const int r4    = lane >> 2;
    const int p4    = lane & 3;
    const int row16 = lane & 15;
    const int quad  = lane >> 4;

    const int m0 = blockIdx.y * 128;
    const int n0 = blockIdx.x * 128;
    const int wm = (w >> 1) * 64;
    const int wn = (w & 1) * 64;

    f32x4 acc[4][4];
#pragma unroll
    for (int i = 0; i < 4; ++i)
#pragma unroll
        for (int j = 0; j < 4; ++j)
            acc[i][j] = (f32x4){0.f, 0.f, 0.f, 0.f};

    for (int k0 = 0; k0 < 1024; k0 += 32) {
        __syncthreads();
#pragma unroll
        for (int c = 0; c < 2; ++c) {
            const int ml  = w * 32 + c * 16 + r4;
            const int swz = (ml >> 1) & 3;
            const unsigned short* ga = A  + (size_t)(m0 + ml) * 1024 + k0 + ((p4 ^ swz) << 3);
            const unsigned short* gb = Wt + (size_t)(n0 + ml) * 1024 + k0 + ((p4 ^ swz) << 3);
            __builtin_amdgcn_global_load_lds(
                (const __attribute__((address_space(1))) void*)ga,
                (__attribute__((address_space(3))) void*)&As[(w * 32 + c * 16) * 32], 16, 0, 0);
            __builtin_amdgcn_global_load_lds(
                (const __attribute__((address_space(1))) void*)gb,
                (__attribute__((address_space(3))) void*)&Bs[(w * 32 + c * 16) * 32], 16, 0, 0);
        }
        __syncthreads();

        s16x8 af[4], bf[4];
#pragma unroll
        for (int bm = 0; bm < 4; ++bm) {
            const int ml  = wm + bm * 16 + row16;
            const int pos = quad ^ ((ml >> 1) & 3);
            af[bm] = *(const s16x8*)&As[ml * 32 + pos * 8];
        }
#pragma unroll
        for (int bn = 0; bn < 4; ++bn) {
            const int nl  = wn + bn * 16 + row16;
            const int pos = quad ^ ((nl >> 1) & 3);
            bf[bn] = *(const s16x8*)&Bs[nl * 32 + pos * 8];
        }
#pragma unroll
        for (int bm = 0; bm < 4; ++bm)
#pragma unroll
            for (int bn = 0; bn < 4; ++bn)
                acc[bm][bn] = __builtin_amdgcn_mfma_f32_16x16x32_bf16(af[bm], bf[bn], acc[bm][bn], 0, 0, 0);
    }

#pragma unroll
    for (int bm = 0; bm < 4; ++bm) {
        const int row = m0 + wm + bm * 16 + quad * 4;
#pragma unroll
        for (int bn = 0; bn < 4; ++bn) {
            const int col = n0 + wn + bn * 16 + row16;
            const float bb = bias ? bias[col] : 0.f;
#pragma unroll
            for (int r = 0; r < 4; ++r) {
                float val = acc[bm][bn][r] + bb;
                if (mode == 1) val = 1.f / (1.f + __expf(-val));
                if (mode == 2) Y16[(size_t)(row + r) * 1024 + col] = f2b_rne(val);
                else           Yf [(size_t)(row + r) * 1024 + col] = val;
            }
        }
    }
}

// ---------------------------------------------------------------------------
// Prep: L2-normalize K,V rows; emit K16 (bf16 normalized K) and P16 packed
// (lr, lr*v_norm) bf16 pairs (one uint per element).  No fp32 writebacks.
// ---------------------------------------------------------------------------
__global__ __launch_bounds__(256) void l2norm_prep(const float* __restrict__ Kb,
                                                   const float* __restrict__ Vb,
                                                   const float* __restrict__ LRb,
                                                   unsigned short* __restrict__ K16,
                                                   unsigned int* __restrict__ P16)
{
    const int gtid = blockIdx.x * 256 + threadIdx.x;
    const int row  = gtid >> 6;
    const int lane = threadIdx.x & 63;
    const size_t base = (size_t)row * dh + lane * 2;

    float2 k2 = *(const float2*)&Kb[base];
    float2 v2 = *(const float2*)&Vb[base];
    float2 l2 = *(const float2*)&LRb[base];
    float sk = k2.x * k2.x + k2.y * k2.y;
    float sv = v2.x * v2.x + v2.y * v2.y;
#pragma unroll
    for (int off = 1; off < 64; off <<= 1) {
        sk += __shfl_xor(sk, off);
        sv += __shfl_xor(sv, off);
    }
    const float rk = 1.f / fmaxf(sqrtf(sk), 1e-12f);
    const float rv = 1.f / fmaxf(sqrtf(sv), 1e-12f);
    k2.x *= rk; k2.y *= rk;
    v2.x *= rv; v2.y *= rv;

    const unsigned int pk = (unsigned int)f2b_rne(k2.x) |
                            ((unsigned int)f2b_rne(k2.y) << 16);
    ((unsigned int*)K16)[base >> 1] = pk;

    uint2 pp;
    pp.x = (unsigned int)f2b_rne(l2.x) | ((unsigned int)f2b_rne(l2.x * v2.x) << 16);
    pp.y = (unsigned int)f2b_rne(l2.y) | ((unsigned int)f2b_rne(l2.y * v2.y) << 16);
    *(uint2*)&P16[base] = pp;
}

// ---------------------------------------------------------------------------
// Pass 1: serial coef-only scan (bf16 inputs).
// Wave = 2 rows x 32 lanes, 4 state cols/lane.  2048 waves (2/SIMD).
// Ring-16 prefetch indexed ONLY by the unrolled induction var u (compile-time)
// -> stays in VGPRs.  (R7's (t+u)&15 runtime index put the ring in scratch:
// VGPR 32, WRITE_SIZE 1.17 GB, 2x regression.)
// Per step: 2 loads (k bf16x4 = 8B, (lr,lrv) = 4B), d1 = w.k, butterfly
// (4 DPP + 1 swizzle), coef = lrv - lr*d1, w += coef*k.
// U transposed [bh, i, t] bf16; W checkpointed bf16 at chunk starts.
// ---------------------------------------------------------------------------
__global__ __launch_bounds__(64) void scan_coef(const unsigned short* __restrict__ K16,
                                                const unsigned int* __restrict__ P16,
                                                unsigned short* __restrict__ Ut,
                                                unsigned short* __restrict__ Wcp)
{
    const int bid = blockIdx.x;            // 0..2047
    const int bh  = bid & 31;              // all 64 blocks of a bh on one XCD
    const int rg  = bid >> 5;              // 0..63
    const int lane = threadIdx.x;
    const int rl   = lane >> 5;            // 0..1 (row within wave)
    const int c32  = lane & 31;            // col chunk (4 cols)
    const int row  = rg * 2 + rl;          // 0..127

    const int b = bh >> 3, h = bh & 7;
    const size_t ebase = (size_t)b * Tlen * Dm + (size_t)h * dh;
    const unsigned short* kp = K16 + ebase + c32 * 4;
    const unsigned int*   pp = P16 + ebase + row;
    unsigned short* up = Ut + ((size_t)bh * dh + row) * Tlen;

    float w0 = 0.f, w1 = 0.f, w2 = 0.f, w3 = 0.f;

    // ring-16 prefetch, compile-time indexed
    uint2        krr[16];
    unsigned int pv[16];
#pragma unroll
    for (int u = 0; u < 16; ++u) {
        const size_t off = (size_t)u * Dm;
        krr[u] = *(const uint2*)(kp + off);
        pv[u]  = pp[off];
    }

    float o16[16];

    for (int t = 0; t < Tlen; t += 16) {
        if ((t & (CH - 1)) == 0) {
            const int c = t >> 7;
            uint2 wc;
            wc.x = (unsigned int)f2b_rne(w0) | ((unsigned int)f2b_rne(w1) << 16);
            wc.y = (unsigned int)f2b_rne(w2) | ((unsigned int)f2b_rne(w3) << 16);
            *(uint2*)&Wcp[(((size_t)bh * NCH + c) * dh + row) * dh + c32 * 4] = wc;
        }
#pragma unroll
        for (int u = 0; u < 16; ++u) {
            const uint2 kk = krr[u];
            const unsigned int pvv = pv[u];

            // prefetch distance 16; index u is compile-time
            int tn = t + u + 16; if (tn > Tlen - 1) tn = Tlen - 1;
            const size_t offn = (size_t)tn * Dm;
            krr[u] = *(const uint2*)(kp + offn);
            pv[u]  = pp[offn];

            const float k0 = blo(kk.x), k1 = bhi(kk.x);
            const float k2 = blo(kk.y), k3 = bhi(kk.y);
            const float lr  = blo(pvv);
            const float lrv = bhi(pvv);

            float d1 = fmaf(w1, k1, w0 * k0) + fmaf(w3, k3, w2 * k2);
            d1 = DPP_ADD(d1, 0xB1);    // xor1
            d1 = DPP_ADD(d1, 0x4E);    // xor2
            d1 = DPP_ADD(d1, 0x141);   // xor4 (half-mirror)
            d1 = DPP_ADD(d1, 0x140);   // xor8 (row-mirror)
            d1 = SWZ_ADD16(d1);        // xor16 -> all 32 lanes of the row

            const float coef = fmaf(-lr, d1, lrv);
            w0 = fmaf(coef, k0, w0); w1 = fmaf(coef, k1, w1);
            w2 = fmaf(coef, k2, w2); w3 = fmaf(coef, k3, w3);
            o16[u] = coef;
        }
        // coef is row-uniform: lane 0 packs 16 bf16 -> two 16B stores
        if (c32 == 0) {
            uint4 pk0, pk1;
            pk0.x = (unsigned int)f2b_rne(o16[0])  | ((unsigned int)f2b_rne(o16[1])  << 16);
            pk0.y = (unsigned int)f2b_rne(o16[2])  | ((unsigned int)f2b_rne(o16[3])  << 16);
            pk0.z = (unsigned int)f2b_rne(o16[4])  | ((unsigned int)f2b_rne(o16[5])  << 16);
            pk0.w = (unsigned int)f2b_rne(o16[6])  | ((unsigned int)f2b_rne(o16[7])  << 16);
            pk1.x = (unsigned int)f2b_rne(o16[8])  | ((unsigned int)f2b_rne(o16[9])  << 16);
            pk1.y = (unsigned int)f2b_rne(o16[10]) | ((unsigned int)f2b_rne(o16[11]) << 16);
            pk1.z = (unsigned int)f2b_rne(o16[12]) | ((unsigned int)f2b_rne(o16[13]) << 16);
            pk1.w = (unsigned int)f2b_rne(o16[14]) | ((unsigned int)f2b_rne(o16[15]) << 16);
            *(uint4*)&up[t]     = pk0;
            *(uint4*)&up[t + 8] = pk1;
        }
    }
}

// ---------------------------------------------------------------------------
// Pass 2: per 128-chunk output via MFMA.
//   S = mask_{s<=t}(Q_c K_c^T)  (bf16 in LDS, +8 pad)
//   O = S @ U_c + Q_c @ Wcp^T   -> Obb (bf16, [b,t,h,i])
// ---------------------------------------------------------------------------
__global__ __launch_bounds__(256) void chunk_o(const unsigned short* __restrict__ Q16,
                                               const unsigned short* __restrict__ K16,
                                               const unsigned short* __restrict__ Ut,
                                               const unsigned short* __restrict__ Wcp,
                                               unsigned short* __restrict__ Obb)
{
    __shared__ __align__(16) unsigned short As[128 * 32];
    __shared__ __align__(16) unsigned short Bs[128 * 32];
    __shared__ __align__(16) unsigned short Sb[128 * 136];   // +8 pad

    const int blk = blockIdx.x;
    const int c   = blk & (NCH - 1);
    const int bh  = blk >> 4;
    const int b   = bh >> 3, h = bh & 7;

    const int tid   = threadIdx.x;
    const int w     = tid >> 6;
    const int lane  = tid & 63;
    const int r4    = lane >> 2;
    const int p4    = lane & 3;
    const int row16 = lane & 15;
    const int quad  = lane >> 4;
    const int wm = (w >> 1) * 64;
    const int wn = (w & 1) * 64;

    const size_t qkbase = (size_t)b * Tlen * Dm + (size_t)(c * CH) * Dm + (size_t)h * dh;
    const size_t ubase  = (size_t)bh * dh * Tlen + (size_t)c * CH;
    const size_t wbase  = ((size_t)bh * NCH + c) * dh * dh;

    f32x4 acc[4][4];
#pragma unroll
    for (int i = 0; i < 4; ++i)
#pragma unroll
        for (int j = 0; j < 4; ++j)
            acc[i][j] = (f32x4){0.f, 0.f, 0.f, 0.f};

    // ---- Stage 1: S = Q K^T
    for (int k0 = 0; k0 < 128; k0 += 32) {
        __syncthreads();
#pragma unroll
        for (int cc = 0; cc < 2; ++cc) {
            const int ml  = w * 32 + cc * 16 + r4;
            const int swz = (ml >> 1) & 3;
            const unsigned short* ga = Q16 + qkbase + (size_t)ml * Dm + k0 + ((p4 ^ swz) << 3);
            const unsigned short* gb = K16 + qkbase + (size_t)ml * Dm + k0 + ((p4 ^ swz) << 3);
            __builtin_amdgcn_global_load_lds(
                (const __attribute__((address_space(1))) void*)ga,
                (__attribute__((address_space(3))) void*)&As[(w * 32 + cc * 16) * 32], 16, 0, 0);
            __builtin_amdgcn_global_load_lds(
                (const __attribute__((address_space(1))) void*)gb,
                (__attribute__((address_space(3))) void*)&Bs[(w * 32 + cc * 16) * 32], 16, 0, 0);
        }
        __syncthreads();

        s16x8 af[4], bf[4];
#pragma unroll
        for (int bm = 0; bm < 4; ++bm) {
            const int ml  = wm + bm * 16 + row16;
            const int pos = quad ^ ((ml >> 1) & 3);
            af[bm] = *(const s16x8*)&As[ml * 32 + pos * 8];
        }
#pragma unroll
        for (int bn = 0; bn < 4; ++bn) {
            const int nl  = wn + bn * 16 + row16;
            const int pos = quad ^ ((nl >> 1) & 3);
            bf[bn] = *(const s16x8*)&Bs[nl * 32 + pos * 8];
        }
#pragma unroll
        for (int bm = 0; bm < 4; ++bm)
#pragma unroll
            for (int bn = 0; bn < 4; ++bn)
                acc[bm][bn] = __builtin_amdgcn_mfma_f32_16x16x32_bf16(af[bm], bf[bn], acc[bm][bn], 0, 0, 0);
    }

    // mask (s <= t), convert, write to Sb; reset acc
#pragma unroll
    for (int bm = 0; bm < 4; ++bm) {
#pragma unroll
        for (int bn = 0; bn < 4; ++bn) {
            const int s_loc = wn + bn * 16 + row16;
#pragma unroll
            for (int r = 0; r < 4; ++r) {
                const int t_loc = wm + bm * 16 + quad * 4 + r;
                const float val = (s_loc <= t_loc) ? acc[bm][bn][r] : 0.f;
                Sb[t_loc * 136 + s_loc] = f2b_rne(val);
            }
            acc[bm][bn] = (f32x4){0.f, 0.f, 0.f, 0.f};
        }
    }

    // ---- Stage 2a: O += S @ U
    for (int k0 = 0; k0 < 128; k0 += 32) {
        __syncthreads();
#pragma unroll
        for (int cc = 0; cc < 2; ++cc) {
            const int nl  = w * 32 + cc * 16 + r4;
            const int swz = (nl >> 1) & 3;
            const unsigned short* gb = Ut + ubase + (size_t)nl * Tlen + k0 + ((p4 ^ swz) << 3);
            __builtin_amdgcn_global_load_lds(
                (const __attribute__((address_space(1))) void*)gb,
                (__attribute__((address_space(3))) void*)&Bs[(w * 32 + cc * 16) * 32], 16, 0, 0);
        }
        __syncthreads();

        s16x8 af[4], bf[4];
#pragma unroll
        for (int bm = 0; bm < 4; ++bm) {
            const int ml = wm + bm * 16 + row16;
            af[bm] = *(const s16x8*)&Sb[ml * 136 + k0 + quad * 8];
        }
#pragma unroll
        for (int bn = 0; bn < 4; ++bn) {
            const int nl  = wn + bn * 16 + row16;
            const int pos = quad ^ ((nl >> 1) & 3);
            bf[bn] = *(const s16x8*)&Bs[nl * 32 + pos * 8];
        }
#pragma unroll
        for (int bm = 0; bm < 4; ++bm)
#pragma unroll
            for (int bn = 0; bn < 4; ++bn)
                acc[bm][bn] = __builtin_amdgcn_mfma_f32_16x16x32_bf16(af[bm], bf[bn], acc[bm][bn], 0, 0, 0);
    }

    // ---- Stage 2b: O += Q @ Wcp^T
    for (int k0 = 0; k0 < 128; k0 += 32) {
        __syncthreads();
#pragma unroll
        for (int cc = 0; cc < 2; ++cc) {
            const int ml  = w * 32 + cc * 16 + r4;
            const int swz = (ml >> 1) & 3;
            const unsigned short* ga = Q16 + qkbase + (size_t)ml * Dm + k0 + ((p4 ^ swz) << 3);
            const unsigned short* gb = Wcp + wbase + (size_t)ml * dh + k0 + ((p4 ^ swz) << 3);
            __builtin_amdgcn_global_load_lds(
                (const __attribute__((address_space(1))) void*)ga,
                (__attribute__((address_space(3))) void*)&As[(w * 32 + cc * 16) * 32], 16, 0, 0);
            __builtin_amdgcn_global_load_lds(
                (const __attribute__((address_space(1))) void*)gb,
                (__attribute__((address_space(3))) void*)&Bs[(w * 32 + cc * 16) * 32], 16, 0, 0);
        }
        __syncthreads();

        s16x8 af[4], bf[4];
#pragma unroll
        for (int bm = 0; bm < 4; ++bm) {
            const int ml  = wm + bm * 16 + row16;
            const int pos = quad ^ ((ml >> 1) & 3);
            af[bm] = *(const s16x8*)&As[ml * 32 + pos * 8];
        }
#pragma unroll
        for (int bn = 0; bn < 4; ++bn) {
            const int nl  = wn + bn * 16 + row16;
            const int pos = quad ^ ((nl >> 1) & 3);
            bf[bn] = *(const s16x8*)&Bs[nl * 32 + pos * 8];
        }
#pragma unroll
        for (int bm = 0; bm < 4; ++bm)
#pragma unroll
            for (int bn = 0; bn < 4; ++bn)
                acc[bm][bn] = __builtin_amdgcn_mfma_f32_16x16x32_bf16(af[bm], bf[bn], acc[bm][bn], 0, 0, 0);
    }

    // epilogue: Obb[b, c*128 + t_loc, h, i_loc] bf16
#pragma unroll
    for (int bm = 0; bm < 4; ++bm) {
#pragma unroll
        for (int bn = 0; bn < 4; ++bn) {
            const int i_loc = wn + bn * 16 + row16;
#pragma unroll
            for (int r = 0; r < 4; ++r) {
                const int t_loc = wm + bm * 16 + quad * 4 + r;
                Obb[qkbase + (size_t)t_loc * Dm + i_loc] = f2b_rne(acc[bm][bn][r]);
            }
        }
    }
}

// ---------------------------------------------------------------------------
extern "C" void kernel_launch(void* const* d_in, const int* in_sizes, int n_in,
                              void* d_out, int out_size, void* d_ws, size_t ws_size,
                              hipStream_t stream)
{
    const float* x    = (const float*)d_in[0];
    const float* Wq   = (const float*)d_in[1];
    const float* Wk   = (const float*)d_in[2];
    const float* Wv   = (const float*)d_in[3];
    const float* Wo   = (const float*)d_in[4];
    const float* Wlr  = (const float*)d_in[5];
    const float* b_lr = (const float*)d_in[6];

    float* ws = (float*)d_ws;
    const size_t S  = (size_t)Mrows * Dm;    // 8388608
    const size_t SW = (size_t)Dm * Dm;       // 1048576
    float* Kb  = ws;
    float* Vb  = ws + S;
    float* LRb = ws + 2 * S;
    unsigned short* xb   = (unsigned short*)(ws + 3 * S);  // S bf16
    unsigned short* Wcp  = xb;                             // alias: xb dead before pass 1
    unsigned short* Q16  = xb + S;
    unsigned short* K16  = Q16 + S;
    unsigned short* Ut   = K16 + S;                        // S bf16
    unsigned short* Obb  = Ut + S;
    unsigned short* Wqb  = Obb + S;
    unsigned short* Wkb  = Wqb + SW;
    unsigned short* Wvb  = Wkb + SW;
    unsigned short* Wlrb = Wvb + SW;
    unsigned short* Wob  = Wlrb + SW;
    unsigned int*   P16  = (unsigned int*)(Wob + SW);      // S uints

    cvt_f32_bf16<<<S / 1024, 256, 0, stream>>>(x, xb);
    cvt_f32_bf16<<<SW / 1024, 256, 0, stream>>>(Wq, Wqb);
    cvt_f32_bf16<<<SW / 1024, 256, 0, stream>>>(Wk, Wkb);
    cvt_f32_bf16<<<SW / 1024, 256, 0, stream>>>(Wv, Wvb);
    cvt_f32_bf16<<<SW / 1024, 256, 0, stream>>>(Wlr, Wlrb);
    cvt_f32_bf16<<<SW / 1024, 256, 0, stream>>>(Wo, Wob);

    dim3 gg(Dm / 128, Mrows / 128);   // (8, 64)
    gemm_bf16<<<gg, 256, 0, stream>>>(xb, Wqb, nullptr, nullptr, Q16, 2);  // Q -> bf16 only
    gemm_bf16<<<gg, 256, 0, stream>>>(xb, Wkb, nullptr, Kb, nullptr, 0);
    gemm_bf16<<<gg, 256, 0, stream>>>(xb, Wvb, nullptr, Vb, nullptr, 0);
    gemm_bf16<<<gg, 256, 0, stream>>>(xb, Wlrb, b_lr, LRb, nullptr, 1);    // fused sigmoid

    l2norm_prep<<<(Bsz * Tlen * Hh) / 4, 256, 0, stream>>>(Kb, Vb, LRb, K16, P16);

    scan_coef<<<Bsz * Hh * 64, 64, 0, stream>>>(K16, P16, Ut, Wcp);

    chunk_o<<<Bsz * Hh * NCH, 256, 0, stream>>>(Q16, K16, Ut, Wcp, Obb);

    gemm_bf16<<<gg, 256, 0, stream>>>(Obb, Wob, nullptr, (float*)d_out, nullptr, 0);
}